// Round 22
// baseline (120.190 us; speedup 1.0000x reference)
//
#include <hip/hip_runtime.h>
#include <math.h>

#define BB 4
#define LL 512000
#define NF 512
#define TT 3997
#define FF 257
#define TWO_PI 6.28318530717958647692f
#define PI_F 3.14159265358979323846f
// fl32(2*pi) — what the f32 numpy port uses building theta and window args:
#define TPI_F32 6.28318548202514648f

static const size_t SPEC_N = (size_t)BB * FF * TT;   // 4,108,916
static const size_t BNT    = (size_t)BB * NF * TT;   // 8,185,856
// layout B (confirmed r11): spec | stft real-part (BNT) | real | imag | phase

#define AB_IM  3.0e-5f
#define RE_MAX 1.0e-4f
#define Z2_MIN 1.0e-8f

__device__ __forceinline__ float neg_zero() { return __uint_as_float(0x80000000u); }

// Barriered ops: exactly one IEEE-RN rounding each (stops -ffp-contract=fast
// from fusing where numpy has separate ops).
__device__ __forceinline__ float mulrn(float a, float b) { float t = a * b; asm("" : "+v"(t)); return t; }
__device__ __forceinline__ float addrn(float a, float b) { float t = a + b; asm("" : "+v"(t)); return t; }
// Single-rounded fused a*b+c (npyv_muladd on AVX512 = FMA):
__device__ __forceinline__ float fmarn(float a, float b, float c) { float t = fmaf(a, b, c); asm("" : "+v"(t)); return t; }

// np f32 theta: fl32(fl32(2pi)*k)/512  (k = f*n < 2^24 exact; /512 exact)
__device__ __forceinline__ float theta32(int k) {
    return mulrn(TPI_F32, (float)k) / 512.0f;
}

__device__ __forceinline__ int bitrev6(int l) { return (int)(__brev((unsigned)l) >> 26); }

// exrow swizzle: XOR bits5-7 onto bits0-2 — conflict-tamed staging.
__device__ __forceinline__ int exr_idx(int n) { return n ^ ((n >> 5) & 7); }

// Intra-wave LDS wait for the per-wave-divergent gold branch ONLY (R13-proven
// pattern; __syncthreads would deadlock there). Rule #18: sched_barrier after.
#define GOLD_SYNC() do { asm volatile("s_waitcnt lgkmcnt(0)" ::: "memory"); \
                         __builtin_amdgcn_sched_barrier(0); } while (0)

// _mm512_reduce_add_ps tree over 16 partials held by lanes base..base+15
__device__ __forceinline__ float hsum16(float s, int base) {
    float q[4];
#pragma unroll
    for (int k = 0; k < 4; ++k) {
        float a = addrn(__shfl(s, base + k),     __shfl(s, base + k + 8));
        float b = addrn(__shfl(s, base + k + 4), __shfl(s, base + k + 12));
        q[k] = addrn(a, b);
    }
    return addrn(addrn(q[0], q[2]), addrn(q[1], q[3]));
}

// ---------------------------------------------------------------------------
// Setup (1 block, 512 threads): s256 table + bit-exact gold window weights at
// frac = 0. Gold sequence = R13-proven: f32 ops, f64-rounded cos, thread-0
// sequential psum, f32 division (+pow).
__global__ void dstft_setup(
    const float* __restrict__ p_winlen,
    const float* __restrict__ p_winpow,
    float* __restrict__ s256g, float* __restrict__ wgold)
{
    __shared__ float tmp[NF];
    __shared__ float psh;
    int n = threadIdx.x;   // 512 threads
    s256g[n] = (float)sin((double)theta32(256 * n));

    float wl   = fminf(fmaxf(p_winlen[0], (float)(512.0 / 20.0)), 512.0f);
    float wpow = p_winpow[0];
    float g_shift = mulrn(addrn(wl - 512.0f, 1.0f), 0.5f);
    float g_lower = floorf(mulrn(511.0f - wl, 0.5f));
    float g_upper = ceilf (mulrn(511.0f + wl, 0.5f));
    float base = (float)n;                       // frac = 0
    float w = 0.0f;
    if (base > g_lower && base < g_upper) {
        float arg = mulrn(TPI_F32, addrn(base, g_shift)) / wl;
        w = 0.5f - mulrn(0.5f, (float)cos((double)arg));
    }
    tmp[n] = w;
    __syncthreads();
    if (n == 0) {
        float ps = 0.0f;
#pragma unroll 1
        for (int i = 0; i < NF; ++i) ps = addrn(ps, tmp[i]);
        psh = ps;
    }
    __syncthreads();
    float ww = w / psh;                          // np: tap / sum (f32 div)
    if (wpow != 1.0f) ww = powf(ww, wpow);
    wgold[n] = ww;
}

// ---------------------------------------------------------------------------
// One frame. DIF across lanes (natural input from registers, no LDS read-back;
// R15-proven butterflies). Output S[j] = F[k + 64*j], k = bitrev6(lane).
// Physical store slot = lane + 64*j; logical f = k + 64*j (epilogue permutes).
__device__ __forceinline__ void dstft_frame_compute(
    const float* __restrict__ xb, int i0, float frac,
    float wl, float wpow, bool dopow, bool tableOK,
    const float* __restrict__ s256f, const float* __restrict__ wlds,
    float* __restrict__ exrow,
    int lane, int rb, bool active, float2* S, float* nyq_out)
{
    // ---- coalesced loads: lane l owns n = 8*l .. 8*l+7
    int nb = i0 + 8 * lane;
    float xr[8];
    if (active && nb >= 0 && nb + 7 < LL && ((i0 & 3) == 0)) {
        float4 p0 = *reinterpret_cast<const float4*>(xb + nb);
        float4 p1 = *reinterpret_cast<const float4*>(xb + nb + 4);
        xr[0] = p0.x; xr[1] = p0.y; xr[2] = p0.z; xr[3] = p0.w;
        xr[4] = p1.x; xr[5] = p1.y; xr[6] = p1.z; xr[7] = p1.w;
    } else {
#pragma unroll
        for (int a = 0; a < 8; ++a) {
            int idx = nb + a;
            xr[a] = (active && idx >= 0 && idx < LL) ? xb[idx] : 0.0f;
        }
    }

    // ---- window weights
    float wwf[8];
    if (tableOK) {
#pragma unroll
        for (int a = 0; a < 8; ++a) wwf[a] = wlds[8 * lane + a];
    } else {
        float shift = (wl - 511.0f) * 0.5f;
        float lower = floorf((511.0f - wl) * 0.5f);
        float upper = ceilf ((511.0f + wl) * 0.5f);
        float psum = 0.0f;
#pragma unroll
        for (int a = 0; a < 8; ++a) {
            int n = 8 * lane + a;
            float base = (float)n - frac;
            float w = 0.0f;
            if (base > lower && base < upper)
                w = 0.5f - 0.5f * __cosf(TWO_PI * (base + shift) / wl);
            wwf[a] = w;
            psum += w;
        }
#pragma unroll
        for (int off = 32; off > 0; off >>= 1) psum += __shfl_xor(psum, off);
        float inv = 1.0f / psum;
#pragma unroll
        for (int a = 0; a < 8; ++a) {
            float w = wwf[a] * inv;
            if (dopow) w = powf(w, wpow);
            wwf[a] = w;
        }
    }

    // ---- taps: registers (FFT input) + LDS staging (for npyv dots)
    float tap[8];
#pragma unroll
    for (int a = 0; a < 8; ++a) {
        tap[a] = mulrn(xr[a], wwf[a]);          // tableOK: bit-exact gold tap
        exrow[exr_idx(8 * lane + a)] = tap[a];
    }

    // ---- 4 packed real-pair 64-pt DIF DFTs across lanes (natural input,
    // bitrev output — R15-proven). z_c = tap[2c] + i*tap[2c+1].
    float2 z[4];
#pragma unroll
    for (int c = 0; c < 4; ++c) z[c] = make_float2(tap[2 * c], tap[2 * c + 1]);
#pragma unroll
    for (int st = 0; st < 6; ++st) {
        int h = 32 >> st;
        int pos = lane & (h - 1);
        bool hi = (lane & h) != 0;
        float ss, sc;
        __sincosf(-PI_F * (float)pos / (float)h, &ss, &sc);
#pragma unroll
        for (int c = 0; c < 4; ++c) {
            float px = __shfl_xor(z[c].x, h);
            float py = __shfl_xor(z[c].y, h);
            if (hi) {
                float rx = px - z[c].x, ry = py - z[c].y;
                z[c] = make_float2(rx * sc - ry * ss, rx * ss + ry * sc);
            } else {
                z[c] = make_float2(z[c].x + px, z[c].y + py);
            }
        }
    }
    // lane now holds Z_c[k], k = bitrev6(lane) = rb.

    // ---- hermitian unpack + twiddle W512^{a*k} (2-reg chain)
    float2 Bv[8];
    {
        int srcl = bitrev6((64 - rb) & 63);   // lane holding Z[(64-k)%64]
#pragma unroll
        for (int c = 0; c < 4; ++c) {
            float rx = __shfl(z[c].x, srcl), ry = __shfl(z[c].y, srcl);
            Bv[2 * c]     = make_float2(0.5f * (z[c].x + rx), 0.5f * (z[c].y - ry));
            Bv[2 * c + 1] = make_float2(0.5f * (z[c].y + ry), -0.5f * (z[c].x - rx));
        }
        float b1s, b1c;
        __sincosf(-(TWO_PI / 512.0f) * (float)rb, &b1s, &b1c);
        float cc = b1c, ss = b1s;
#pragma unroll
        for (int a = 1; a < 8; ++a) {
            float vx = Bv[a].x, vy = Bv[a].y;
            Bv[a] = make_float2(vx * cc - vy * ss, vx * ss + vy * cc);
            if (a < 7) {
                float nc = cc * b1c - ss * b1s;
                float ns = cc * b1s + ss * b1c;
                cc = nc; ss = ns;
            }
        }
    }
    // ---- 8-pt complex DFT over slots: S[j] = F[k + 64*j]
    {
        const float Cq = 0.70710678118654752440f;
        float ex0 = Bv[0].x + Bv[4].x, ey0 = Bv[0].y + Bv[4].y;
        float dx0 = Bv[0].x - Bv[4].x, dy0 = Bv[0].y - Bv[4].y;
        float ex1 = Bv[2].x + Bv[6].x, ey1 = Bv[2].y + Bv[6].y;
        float dx1 = Bv[2].x - Bv[6].x, dy1 = Bv[2].y - Bv[6].y;
        float2 E0 = make_float2(ex0 + ex1, ey0 + ey1);
        float2 E2 = make_float2(ex0 - ex1, ey0 - ey1);
        float2 E1 = make_float2(dx0 + dy1, dy0 - dx1);
        float2 E3 = make_float2(dx0 - dy1, dy0 + dx1);
        float ox0 = Bv[1].x + Bv[5].x, oy0 = Bv[1].y + Bv[5].y;
        float qx0 = Bv[1].x - Bv[5].x, qy0 = Bv[1].y - Bv[5].y;
        float ox1 = Bv[3].x + Bv[7].x, oy1 = Bv[3].y + Bv[7].y;
        float qx1 = Bv[3].x - Bv[7].x, qy1 = Bv[3].y - Bv[7].y;
        float2 O0 = make_float2(ox0 + ox1, oy0 + oy1);
        float2 O2 = make_float2(ox0 - ox1, oy0 - oy1);
        float2 O1 = make_float2(qx0 + qy1, qy0 - qx1);
        float2 O3 = make_float2(qx0 - qy1, qy0 + qx1);
        float2 T0 = O0;
        float2 T1 = make_float2(Cq * (O1.x + O1.y), Cq * (O1.y - O1.x));
        float2 T2 = make_float2(O2.y, -O2.x);
        float2 T3 = make_float2(Cq * (O3.y - O3.x), -Cq * (O3.x + O3.y));
        S[0] = make_float2(E0.x + T0.x, E0.y + T0.y);
        S[4] = make_float2(E0.x - T0.x, E0.y - T0.y);
        S[1] = make_float2(E1.x + T1.x, E1.y + T1.y);
        S[5] = make_float2(E1.x - T1.x, E1.y - T1.y);
        S[2] = make_float2(E2.x + T2.x, E2.y + T2.y);
        S[6] = make_float2(E2.x - T2.x, E2.y - T2.y);
        S[3] = make_float2(E3.x + T3.x, E3.y + T3.y);
        S[7] = make_float2(E3.x - T3.x, E3.y - T3.y);
    }
    __syncthreads();   // exrow staging visible (uniform path — compiler-safe)

    // ---- gated npyv Nyquist dot. F[256] lives at lane 0 (k=0), j=4.
    float s4x0 = __shfl(S[4].x, 0);
    bool need_nyq = active && (s4x0 < RE_MAX);   // wave-uniform
    if (need_nyq) {
        float s = 0.0f;
        if (lane < 16) {
#pragma unroll
            for (int i = 0; i < 8; ++i) {
                int base = 64 * i + lane;
                s = fmarn(exrow[exr_idx(base +  0)], s256f[base +  0], s);
                s = fmarn(exrow[exr_idx(base + 16)], s256f[base + 16], s);
                s = fmarn(exrow[exr_idx(base + 32)], s256f[base + 32], s);
                s = fmarn(exrow[exr_idx(base + 48)], s256f[base + 48], s);
            }
        }
        *nyq_out = -hsum16(s, 0);
    } else {
        *nyq_out = __shfl(S[4].y, 0);   // fast value, within tolerance
    }

    // ---- flag scan: logical f = bitrev6(lane) + 64*j; phase bins f<=256.
    // Ranges per j are identical to before (bitrev6 is a bijection on 0..63):
    // j<4 -> f in 64j..64j+63; (lane0,j0) -> f=0; (lane0,j4) -> f=256.
    unsigned long long flags[5];
    unsigned long long anyf = 0ULL;
#pragma unroll
    for (int j = 0; j < 5; ++j) {
        float2 vv = S[j];
        bool flg = false;
        if (active) {
            if (j == 0 && lane == 0)      flg = fabsf(vv.x) < RE_MAX;   // f=0
            else if (j == 4)              flg = (lane == 0) && (fabsf(vv.x) < RE_MAX); // f=256
            else                          flg = (fabsf(vv.y) < AB_IM && vv.x < RE_MAX) ||
                                                (vv.x * vv.x + vv.y * vv.y < Z2_MIN);
        }
        flags[j] = __ballot(flg);
        anyf |= flags[j];
    }

    if (anyf) {   // per-wave divergent: GOLD_SYNC only (no __syncthreads here)
        if (!tableOK) {
            // full gold window + sequential psum + gold taps (R13 sequence)
            float g_shift = mulrn(addrn(wl - 512.0f, 1.0f), 0.5f);
            float g_lower = floorf(mulrn(511.0f - wl, 0.5f));
            float g_upper = ceilf (mulrn(511.0f + wl, 0.5f));
            float gw[8];
#pragma unroll
            for (int a = 0; a < 8; ++a) {
                int n = 8 * lane + a;
                float base = (float)n - frac;
                float w = 0.0f;
                if (base > g_lower && base < g_upper) {
                    float arg = mulrn(TPI_F32, addrn(base, g_shift)) / wl;
                    w = 0.5f - mulrn(0.5f, (float)cos((double)arg));
                }
                gw[a] = w;
                exrow[exr_idx(n)] = w;
            }
            GOLD_SYNC();
            float ps = 0.0f;
            if (lane == 0) {
#pragma unroll 1
                for (int n = 0; n < NF; ++n) ps = addrn(ps, exrow[exr_idx(n)]);
            }
            ps = __shfl(ps, 0);
#pragma unroll
            for (int a = 0; a < 8; ++a) {
                int n = 8 * lane + a;
                float w = gw[a] / ps;
                if (dopow) w = powf(w, wpow);
                exrow[exr_idx(n)] = mulrn(xr[a], w);
            }
            GOLD_SYNC();
        }
        // taps in exrow are gold now. Flagged-bin npyv dots (logical f):
#pragma unroll
        for (int j = 0; j < 5; ++j) {
            unsigned long long m = flags[j];
            while (m) {
                int src = (int)(__ffsll(m) - 1);
                m &= m - 1;
                int ff = bitrev6(src) + 64 * j;   // logical frequency
                float s = 0.0f;
                if (lane < 32) {
                    int L = lane & 15;
                    bool isCos = lane >= 16;
#pragma unroll 1
                    for (int i = 0; i < 8; ++i) {
                        int base = 64 * i + L;
#pragma unroll
                        for (int Bq = 0; Bq < 4; ++Bq) {
                            int n = base + 16 * Bq;
                            double sv, cv;
                            sincos((double)theta32(ff * n), &sv, &cv);
                            s = fmarn(exrow[exr_idx(n)], isCos ? (float)cv : (float)sv, s);
                        }
                    }
                }
                float im = hsum16(s, 0);
                float re = hsum16(s, 16);
                if (lane == src) S[j] = make_float2(re, -im);
            }
        }
        // gold nyq from gold taps (only when taps were recomputed)
        if (!tableOK) {
            float s = 0.0f;
            if (lane < 16) {
#pragma unroll 1
                for (int i = 0; i < 8; ++i) {
                    int base = 64 * i + lane;
                    s = fmarn(exrow[exr_idx(base +  0)], s256f[base +  0], s);
                    s = fmarn(exrow[exr_idx(base + 16)], s256f[base + 16], s);
                    s = fmarn(exrow[exr_idx(base + 32)], s256f[base + 32], s);
                    s = fmarn(exrow[exr_idx(base + 48)], s256f[base + 48], s);
                }
            }
            *nyq_out = -hsum16(s, 0);
            GOLD_SYNC();
        }
    }
}

// ---------------------------------------------------------------------------
__global__ __launch_bounds__(256) void dstft_fft_kernel(
    const float* __restrict__ x,
    const float* __restrict__ p_stride,
    const float* __restrict__ p_winlen,
    const float* __restrict__ p_winpow,
    const float* __restrict__ s256g,
    const float* __restrict__ wgold,
    float2* __restrict__ scr, size_t scr_cap)
{
    __shared__ float ex[4][NF];
    __shared__ float s256f[NF];
    __shared__ float wlds[NF];

    const int tid  = threadIdx.x;
    const int wv   = tid >> 6;
    const int lane = tid & 63;

    s256f[tid]       = s256g[tid];
    s256f[tid + 256] = s256g[tid + 256];
    wlds[tid]        = wgold[tid];
    wlds[tid + 256]  = wgold[tid + 256];
    __syncthreads();

    float strd = p_stride[0];
    float wl   = fminf(fmaxf(p_winlen[0], (float)(512.0 / 20.0)), 512.0f);
    float wpow = p_winpow[0];
    const bool dopow = (wpow != 1.0f);

    double strd64 = fmin(fmax((double)strd, 0.0), 512.0);

    const int rb = bitrev6(lane);
    const int b  = blockIdx.y;
    const float* xb = x + (size_t)b * LL;

    const int t = blockIdx.x * 4 + wv;
    const bool active = (t < TT);
    double frame64 = strd64 * (double)t;
    int i0 = (int)floor(frame64);
    double frac64 = frame64 - floor(frame64);
    float frac = (float)frac64;
    const bool tableOK = (frac64 == 0.0);

    float2 S[8];
    float nyq;
    dstft_frame_compute(xb, i0, frac, wl, wpow, dopow, tableOK,
                        s256f, wlds, ex[wv], lane, rb, active, S, &nyq);

    if (active) {
        size_t basez = ((size_t)b * TT + t) * NF;
#pragma unroll
        for (int j = 0; j < 8; ++j) {
            float2 vv = S[j];
            if (j == 0 && lane == 0) vv.y = neg_zero(); // gold: -(+0) = -0.0
            if (j == 4 && lane == 0) vv.y = nyq;        // gold/gated Nyquist
            size_t p = (size_t)(lane + 64 * j);          // PHYSICAL slot
            if (basez + p < scr_cap) scr[basez + p] = vv;
        }
    }
}

// ---------------------------------------------------------------------------
// Epilogue: physical slot p -> logical f = bitrev6(p&63) | (p&~63).
// Reads stay physically contiguous (coalesced); writes stay t-contiguous.
__global__ __launch_bounds__(256) void dstft_epilogue(
    const float2* __restrict__ scr, size_t scr_cap,
    float* __restrict__ out, size_t oe, int layoutB)
{
    __shared__ float2 tile[32][33];
    const int tx = threadIdx.x;          // 0..31
    const int ty = threadIdx.y;          // 0..7
    const int t0 = blockIdx.x * 32;
    const int f0 = blockIdx.y * 32;      // physical block
    const int b  = blockIdx.z;

#pragma unroll
    for (int i = 0; i < 4; ++i) {
        int tl = ty + 8 * i;
        int t  = t0 + tl;
        float2 v = make_float2(0.0f, 0.0f);
        size_t si = ((size_t)b * TT + t) * NF + (f0 + tx);
        if (t < TT && si < scr_cap) v = scr[si];
        tile[tl][tx] = v;
    }
    __syncthreads();

    const size_t off_stft  = SPEC_N;
    const size_t off_real  = layoutB ? (SPEC_N + BNT) : (SPEC_N + 2 * BNT);
    const size_t off_imag  = off_real + BNT;
    const size_t off_phase = off_imag + BNT;

#pragma unroll
    for (int i = 0; i < 4; ++i) {
        int fl = ty + 8 * i;
        int p  = f0 + fl;                              // physical row
        int f  = bitrev6(p & 63) | (p & ~63);          // logical frequency
        int t  = t0 + tx;
        if (t >= TT) continue;
        float2 v = tile[tx][fl];
        size_t o = ((size_t)b * NF + f) * TT + t;
        if (off_real + o < oe) out[off_real + o] = v.x;
        if (off_imag + o < oe) out[off_imag + o] = v.y;
        if (layoutB) {
            if (off_stft + o < oe) out[off_stft + o] = v.x;
        } else {
            size_t os = off_stft + 2 * o;
            if (os + 1 < oe) *reinterpret_cast<float2*>(out + os) = v;
        }
        if (f < FF) {
            size_t o2 = ((size_t)b * FF + f) * TT + t;
            if (o2 < oe) out[o2] = sqrtf(v.x * v.x + v.y * v.y) + 1.1920929e-7f;
            if (off_phase + o2 < oe) out[off_phase + o2] = atan2f(v.y, v.x);
        }
    }
}

// ---------------------------------------------------------------------------
// Fallback (ws too small): fused compute + direct writes (no table).
__global__ __launch_bounds__(256) void dstft_fused(
    const float* __restrict__ x,
    const float* __restrict__ p_stride,
    const float* __restrict__ p_winlen,
    const float* __restrict__ p_winpow,
    float* __restrict__ out, size_t oe, int layoutB)
{
    __shared__ float ex[4][NF];
    __shared__ float s256f[NF];

    const int tid  = threadIdx.x;
    const int wv   = tid >> 6;
    const int lane = tid & 63;

    for (int k = tid; k < NF; k += 256)
        s256f[k] = (float)sin((double)theta32(256 * k));
    __syncthreads();

    float strd = p_stride[0];
    float wl   = fminf(fmaxf(p_winlen[0], (float)(512.0 / 20.0)), 512.0f);
    float wpow = p_winpow[0];
    const bool dopow = (wpow != 1.0f);

    double strd64 = fmin(fmax((double)strd, 0.0), 512.0);
    const int rb = bitrev6(lane);
    const int b  = blockIdx.y;
    const float* xb = x + (size_t)b * LL;

    const int t = blockIdx.x * 4 + wv;
    const bool active = (t < TT);
    double frame64 = strd64 * (double)t;
    int i0 = (int)floor(frame64);
    float frac = (float)(frame64 - floor(frame64));

    float2 S[8];
    float nyq;
    dstft_frame_compute(xb, i0, frac, wl, wpow, dopow, false,
                        s256f, nullptr, ex[wv], lane, rb, active, S, &nyq);

    if (active) {
        const size_t off_stft  = SPEC_N;
        const size_t off_real  = layoutB ? (SPEC_N + BNT) : (SPEC_N + 2 * BNT);
        const size_t off_imag  = off_real + BNT;
        const size_t off_phase = off_imag + BNT;
#pragma unroll
        for (int j = 0; j < 8; ++j) {
            float2 vv = S[j];
            if (j == 0 && lane == 0) vv.y = neg_zero();
            if (j == 4 && lane == 0) vv.y = nyq;
            int f = rb + 64 * j;                       // logical frequency
            size_t o = ((size_t)b * NF + f) * TT + t;
            if (off_real + o < oe) out[off_real + o] = vv.x;
            if (off_imag + o < oe) out[off_imag + o] = vv.y;
            if (layoutB) {
                if (off_stft + o < oe) out[off_stft + o] = vv.x;
            } else {
                size_t os = off_stft + 2 * o;
                if (os + 1 < oe) { out[os] = vv.x; out[os + 1] = vv.y; }
            }
            if (f < FF) {
                size_t o2 = ((size_t)b * FF + f) * TT + t;
                if (o2 < oe) out[o2] = sqrtf(vv.x * vv.x + vv.y * vv.y) + 1.1920929e-7f;
                if (off_phase + o2 < oe) out[off_phase + o2] = atan2f(vv.y, vv.x);
            }
        }
    }
}

// ---------------------------------------------------------------------------
extern "C" void kernel_launch(void* const* d_in, const int* in_sizes, int n_in,
                              void* d_out, int out_size, void* d_ws, size_t ws_size,
                              hipStream_t stream)
{
    const float* x  = (const float*)d_in[0];
    const float* ps = (const float*)d_in[1];
    const float* pw = (const float*)d_in[2];
    const float* pp = (const float*)d_in[3];
    float* out = (float*)d_out;

    const size_t totalA = 2 * SPEC_N + 4 * BNT;   // 40,961,256
    int layoutB = ((size_t)out_size == totalA) ? 0 : 1;   // confirmed: B

    const size_t oe = (size_t)out_size;
    const size_t scrBytes = BNT * sizeof(float2);              // 65.5 MB
    const size_t needWs   = scrBytes + 2 * NF * sizeof(float); // + tables
    const bool use_ws = (d_ws != nullptr) && (ws_size >= needWs);

    if (use_ws) {
        float2* scr   = (float2*)d_ws;
        float*  s256g = (float*)((char*)d_ws + scrBytes);
        float*  wgold = s256g + NF;
        dstft_setup<<<1, NF, 0, stream>>>(pw, pp, s256g, wgold);
        dstft_fft_kernel<<<dim3((TT + 3) / 4, BB), 256, 0, stream>>>(
            x, ps, pw, pp, s256g, wgold, scr, BNT);
        dstft_epilogue<<<dim3((TT + 31) / 32, NF / 32, BB), dim3(32, 8), 0, stream>>>(
            scr, BNT, out, oe, layoutB);
    } else {
        dstft_fused<<<dim3((TT + 3) / 4, BB), 256, 0, stream>>>(
            x, ps, pw, pp, out, oe, layoutB);
    }
}